// Round 12
// baseline (310.661 us; speedup 1.0000x reference)
//
#include <hip/hip_runtime.h>
#include <hip/hip_bf16.h>

#define N_NODES 10000
#define KP      10240   // K padded; xwt pad slabs are ZERO
#define F       128
#define SPLITS  8
#define KSPLIT  1280    // KP / SPLITS
#define BK      64
#define TPS     20      // tiles per split
#define BM      64
#define MBLK    157     // ceil(10000/64)
#define PROWS   10048   // MBLK*64

typedef float  f32x4  __attribute__((ext_vector_type(4)));
typedef short  bf16x8 __attribute__((ext_vector_type(8)));
typedef short  s16x8  __attribute__((ext_vector_type(8)));

static __device__ __forceinline__ unsigned short f2bf(float f) {
    unsigned u = __builtin_bit_cast(unsigned, f);
    u += 0x7FFFu + ((u >> 16) & 1u);
    return (unsigned short)(u >> 16);
}

static __device__ __forceinline__ bf16x8 pack8(f32x4 lo, f32x4 hi) {
    bf16x8 r;
    r[0] = (short)f2bf(lo[0]); r[1] = (short)f2bf(lo[1]);
    r[2] = (short)f2bf(lo[2]); r[3] = (short)f2bf(lo[3]);
    r[4] = (short)f2bf(hi[0]); r[5] = (short)f2bf(hi[1]);
    r[6] = (short)f2bf(hi[2]); r[7] = (short)f2bf(hi[3]);
    return r;
}

// ---------------------------------------------------------------------------
// Kernel 1: xwt = (X @ W1)^T bf16, tiled+swizzled for direct global_load_lds:
//   16B unit u = kc2*512 + ct*64 + c*4 + ku within each 16KB slab-pair,
//   STORED at position p = u ^ (c&7).  (R8/R9-proven layout.)
// grid 640 x 256; pad k (nodes >= 10000) -> 0.
// ---------------------------------------------------------------------------
__global__ __launch_bounds__(256) void k_xw(const float* __restrict__ x,
                                            const float* __restrict__ W1,
                                            unsigned short* __restrict__ xwt) {
    __shared__ float xs[16][128];
    __shared__ unsigned short ts[16][136];
    const int t  = threadIdx.x;
    const int nb = blockIdx.x * 16;

    #pragma unroll
    for (int i = 0; i < 2; ++i) {
        int idx = t + i * 256;
        int n   = idx >> 5;
        int c4  = idx & 31;
        int gn  = nb + n; if (gn > N_NODES - 1) gn = N_NODES - 1;
        f32x4 v = *reinterpret_cast<const f32x4*>(x + (size_t)gn * F + c4 * 4);
        *reinterpret_cast<f32x4*>(&xs[n][c4 * 4]) = v;
    }
    __syncthreads();

    const int f  = t & 127;
    const int ng = t >> 7;
    float acc[8] = {0.f, 0.f, 0.f, 0.f, 0.f, 0.f, 0.f, 0.f};

    for (int c4 = 0; c4 < 32; ++c4) {
        float w0 = W1[(4 * c4 + 0) * F + f];
        float w1 = W1[(4 * c4 + 1) * F + f];
        float w2 = W1[(4 * c4 + 2) * F + f];
        float w3 = W1[(4 * c4 + 3) * F + f];
        #pragma unroll
        for (int i = 0; i < 8; ++i) {
            f32x4 xv = *reinterpret_cast<const f32x4*>(&xs[ng * 8 + i][c4 * 4]);
            acc[i] = fmaf(xv.x, w0, fmaf(xv.y, w1, fmaf(xv.z, w2, fmaf(xv.w, w3, acc[i]))));
        }
    }

    #pragma unroll
    for (int i = 0; i < 8; ++i) ts[ng * 8 + i][f] = f2bf(acc[i]);
    __syncthreads();

    {
        const int col = t >> 1, half = t & 1;
        s16x8 v8;
        #pragma unroll
        for (int i = 0; i < 8; ++i) {
            int n = half * 8 + i;
            v8[i] = (nb + n < N_NODES) ? (short)ts[n][col] : (short)0;
        }
        const int c  = col & 15, ct = col >> 4;
        const int kc = nb >> 5, khalf = (nb >> 4) & 1;
        const int ku = khalf * 2 + half;
        int upair = (kc & 1) * 512 + ct * 64 + c * 4 + ku;
        size_t off = (size_t)(kc >> 1) * 8192 + (size_t)(upair ^ (c & 7)) * 8;
        *reinterpret_cast<s16x8*>(xwt + off) = v8;
    }
}

// ---------------------------------------------------------------------------
// Kernel 2: partial GEMM, split-K. grid 1256 x 512. split = bid&7 (XCD-affine:
// round-robin dispatch puts each split's 157 blocks on one XCD -> its 327KB
// B-region goes L2-resident). Block 64r x 128c x 1280k, BK=64, TPS=20.
// A: 1KB-per-row DRAM visits (4 tiles) into regs, dribbled to a 5-slot LDS
//    ring (write tile t+3 while computing slot t%5). Full 20-tile unroll so
//    reg-set parity is static. B: gload_lds double-buffer (R9-proven).
// ---------------------------------------------------------------------------
#define GLOAD(gsrc, ldst) __builtin_amdgcn_global_load_lds(                      \
    (const __attribute__((address_space(1))) unsigned int*)(gsrc),               \
    (__attribute__((address_space(3))) unsigned int*)(ldst), 16, 0, 0)

#define MFMA_(a, b, c) __builtin_amdgcn_mfma_f32_16x16x32_bf16(a, b, c, 0, 0, 0)

__global__ __launch_bounds__(512, 2) void k_gcn(const float* __restrict__ A,
                                                const unsigned short* __restrict__ xwt,
                                                float* __restrict__ P) {
    __shared__ __align__(16) unsigned char Bs[2][16384];   // 32 KB
    __shared__ __align__(16) unsigned char As[5][8192];    // 40 KB ring

    const int t    = threadIdx.x;
    const int w    = t >> 6;
    const int lane = t & 63;
    const int l16  = lane & 15;
    const int g    = lane >> 4;
    const int mq   = w >> 2;         // 0..1 : 32-row half
    const int cq   = w & 3;          // 0..3 : 32-col quarter
    const int split = blockIdx.x & 7;        // XCD-affine split
    const int mb    = blockIdx.x >> 3;       // 0..156
    const int rbase = mb * BM;
    const int k0    = split * KSPLIT;

    // ---- A staging: thread t -> row (t>>3), 128B chunk (t&7) of 1KB/row ----
    const int sr = t >> 3, c = t & 7;
    int arow = rbase + sr; if (arow > N_NODES - 1) arow = N_NODES - 1;
    const size_t abase = (size_t)arow * N_NODES + k0 + c * 32;
    const size_t lim4  = (size_t)N_NODES * N_NODES - 4;    // per-f32x4 clamp

    const unsigned char* const xb = reinterpret_cast<const unsigned char*>(xwt);

    // ---- fragment read byte offsets (R9 verbatim) ----
    int ar00, ar01, ar10, ar11;
    {
        int r0 = mq * 32 + l16, r1 = mq * 32 + 16 + l16;
        ar00 = r0 * 128 + ((0 * 4 + g) ^ (r0 & 7)) * 16;
        ar01 = r0 * 128 + ((1 * 4 + g) ^ (r0 & 7)) * 16;
        ar10 = r1 * 128 + ((0 * 4 + g) ^ (r1 & 7)) * 16;
        ar11 = r1 * 128 + ((1 * 4 + g) ^ (r1 & 7)) * 16;
    }
    int br00, br01, br10, br11;
    {
        int m = l16 & 7;
        br00 = ((0 * 512 + (cq * 2 + 0) * 64 + l16 * 4 + g) ^ m) * 16;
        br01 = ((1 * 512 + (cq * 2 + 0) * 64 + l16 * 4 + g) ^ m) * 16;
        br10 = ((0 * 512 + (cq * 2 + 1) * 64 + l16 * 4 + g) ^ m) * 16;
        br11 = ((1 * 512 + (cq * 2 + 1) * 64 + l16 * 4 + g) ^ m) * 16;
    }

    f32x4 acc00 = {0.f, 0.f, 0.f, 0.f}, acc01 = acc00, acc10 = acc00, acc11 = acc00;

    f32x4 s0[8], s1[8];   // two parked 1KB-super register sets (static parity)

#define LOADA(SP, super) do {                                                    \
    size_t _b = abase + (size_t)(super) * 256;                                   \
    _Pragma("unroll")                                                            \
    for (int _j = 0; _j < 8; ++_j) {                                             \
        size_t _o = _b + _j * 4; if (_o > lim4) _o = lim4;                       \
        SP[_j] = __builtin_nontemporal_load(reinterpret_cast<const f32x4*>(A + _o)); \
    }                                                                            \
} while (0)

    // thread's 32 floats belong to tile (c>>1) within its super; units (c&1)*4+j
#define WRITEA(SP, tile) do {                                                    \
    if ((c >> 1) == ((tile) & 3)) {                                              \
        unsigned char* _r = &As[(tile) % 5][0] + sr * 128;                       \
        int _u0 = (c & 1) * 4;                                                   \
        *reinterpret_cast<bf16x8*>(_r + (((_u0+0) ^ (sr&7)) * 16)) = pack8(SP[0], SP[1]); \
        *reinterpret_cast<bf16x8*>(_r + (((_u0+1) ^ (sr&7)) * 16)) = pack8(SP[2], SP[3]); \
        *reinterpret_cast<bf16x8*>(_r + (((_u0+2) ^ (sr&7)) * 16)) = pack8(SP[4], SP[5]); \
        *reinterpret_cast<bf16x8*>(_r + (((_u0+3) ^ (sr&7)) * 16)) = pack8(SP[6], SP[7]); \
    }                                                                            \
} while (0)

#define STAGEB(tile, buf) do {                                                   \
    const unsigned char* _cb = xb + (size_t)(split * 40 + 2 * (tile)) * 8192;    \
    GLOAD(_cb + (w * 2 + 0) * 1024 + lane * 16, &Bs[buf][(w * 2 + 0) * 1024]);   \
    GLOAD(_cb + (w * 2 + 1) * 1024 + lane * 16, &Bs[buf][(w * 2 + 1) * 1024]);   \
} while (0)

#define COMPUTE(slot, buf) do {                                                  \
    const unsigned char* _as = &As[slot][0];                                     \
    bf16x8 af00 = *reinterpret_cast<const bf16x8*>(_as + ar00);                  \
    bf16x8 af01 = *reinterpret_cast<const bf16x8*>(_as + ar01);                  \
    bf16x8 af10 = *reinterpret_cast<const bf16x8*>(_as + ar10);                  \
    bf16x8 af11 = *reinterpret_cast<const bf16x8*>(_as + ar11);                  \
    bf16x8 bf00 = *reinterpret_cast<const bf16x8*>(&Bs[buf][br00]);              \
    bf16x8 bf01 = *reinterpret_cast<const bf16x8*>(&Bs[buf][br01]);              \
    bf16x8 bf10 = *reinterpret_cast<const bf16x8*>(&Bs[buf][br10]);              \
    bf16x8 bf11 = *reinterpret_cast<const bf16x8*>(&Bs[buf][br11]);              \
    acc00 = MFMA_(af00, bf00, acc00); acc00 = MFMA_(af01, bf01, acc00);          \
    acc01 = MFMA_(af00, bf10, acc01); acc01 = MFMA_(af01, bf11, acc01);          \
    acc10 = MFMA_(af10, bf00, acc10); acc10 = MFMA_(af11, bf01, acc10);          \
    acc11 = MFMA_(af10, bf10, acc11); acc11 = MFMA_(af11, bf11, acc11);          \
} while (0)

    // prologue: super0 -> s0, write tiles 0..2; super1 -> s1; B tile 0
    LOADA(s0, 0);
    WRITEA(s0, 0); WRITEA(s0, 1); WRITEA(s0, 2);
    LOADA(s1, 1);
    STAGEB(0, 0);
    __syncthreads();

    // schedule per tile tl: stage B(tl+1); write A tile tl+3 (set ((tl+3)/4)&1);
    // at super starts issue LOADA for super (tl/4)+2 into the just-freed set.
    #pragma unroll
    for (int tl = 0; tl < TPS; ++tl) {
        if (tl + 1 < TPS) STAGEB(tl + 1, (tl + 1) & 1);
        if (tl + 3 < TPS) {
            if (((((tl + 3) >> 2)) & 1) == 0) WRITEA(s0, tl + 3);
            else                              WRITEA(s1, tl + 3);
        }
        if ((tl & 3) == 0 && ((tl >> 2) + 2) < 5) {
            if ((((tl >> 2) + 2) & 1) == 0) LOADA(s0, (tl >> 2) + 2);
            else                            LOADA(s1, (tl >> 2) + 2);
        }
        COMPUTE(tl % 5, tl & 1);
        __syncthreads();
    }

    // ---- write f32 partials (R9 verbatim) ----
    {
        float* Pp = P + ((size_t)split * PROWS + rbase) * F;
        #pragma unroll
        for (int e = 0; e < 4; ++e) {
            Pp[(size_t)(mq * 32 +  0 + g * 4 + e) * F + cq * 32 +      l16] = acc00[e];
            Pp[(size_t)(mq * 32 +  0 + g * 4 + e) * F + cq * 32 + 16 + l16] = acc01[e];
            Pp[(size_t)(mq * 32 + 16 + g * 4 + e) * F + cq * 32 +      l16] = acc10[e];
            Pp[(size_t)(mq * 32 + 16 + g * 4 + e) * F + cq * 32 + 16 + l16] = acc11[e];
        }
    }
#undef LOADA
#undef WRITEA
#undef STAGEB
#undef COMPUTE
}

// ---------------------------------------------------------------------------
// Kernel 3: out[r] = relu(sum_s P[s][r][:] + b1) . W2 + b2. grid 5000 x 256.
// ---------------------------------------------------------------------------
__global__ __launch_bounds__(256) void k_red(const float* __restrict__ P,
                                             const float* __restrict__ b1,
                                             const float* __restrict__ W2,
                                             const float* __restrict__ b2,
                                             float* __restrict__ out) {
    __shared__ float sred[4];
    const int t   = threadIdx.x;
    const int row = blockIdx.x * 2 + (t >> 7);
    const int c   = t & 127;

    float v = 0.f;
    #pragma unroll
    for (int s = 0; s < SPLITS; ++s)
        v += P[((size_t)s * PROWS + row) * F + c];
    v = fmaxf(v + b1[c], 0.f) * W2[c];

    v += __shfl_xor(v, 1);
    v += __shfl_xor(v, 2);
    v += __shfl_xor(v, 4);
    v += __shfl_xor(v, 8);
    v += __shfl_xor(v, 16);
    v += __shfl_xor(v, 32);
    if ((t & 63) == 0) sred[t >> 6] = v;
    __syncthreads();
    if (t < 2) out[blockIdx.x * 2 + t] = sred[t * 2] + sred[t * 2 + 1] + b2[0];
}

extern "C" void kernel_launch(void* const* d_in, const int* in_sizes, int n_in,
                              void* d_out, int out_size, void* d_ws, size_t ws_size,
                              hipStream_t stream) {
    const float* x  = (const float*)d_in[0];
    const float* a  = (const float*)d_in[1];
    const float* W1 = (const float*)d_in[2];
    const float* b1 = (const float*)d_in[3];
    const float* W2 = (const float*)d_in[4];
    const float* b2 = (const float*)d_in[5];
    float* out = (float*)d_out;

    unsigned short* xwt = (unsigned short*)d_ws;                  // 2.62 MB tiled
    float* P = (float*)((char*)d_ws + (size_t)(32 << 20));        // 8x10048x128 f32

    k_xw<<<640, 256, 0, stream>>>(x, W1, xwt);
    k_gcn<<<MBLK * SPLITS, 512, 0, stream>>>(a, xwt, P);
    k_red<<<5000, 256, 0, stream>>>(P, b1, W2, b2, out);
}

// Round 13
// 192.425 us; speedup vs baseline: 1.6144x; 1.6144x over previous
//
#include <hip/hip_runtime.h>
#include <hip/hip_bf16.h>

#define N_NODES 10000
#define KP      10240   // K padded; xwt pad slabs are ZERO
#define F       128
#define SPLITS  8
#define KSPLIT  1280    // KP / SPLITS
#define BK      64
#define TPS     20      // tiles per split
#define BM      64
#define MBLK    157     // ceil(10000/64)
#define PROWS   10048   // MBLK*64

typedef float  f32x4  __attribute__((ext_vector_type(4)));
typedef short  bf16x8 __attribute__((ext_vector_type(8)));
typedef short  s16x8  __attribute__((ext_vector_type(8)));

static __device__ __forceinline__ unsigned short f2bf(float f) {
    unsigned u = __builtin_bit_cast(unsigned, f);
    u += 0x7FFFu + ((u >> 16) & 1u);
    return (unsigned short)(u >> 16);
}

static __device__ __forceinline__ bf16x8 pack8(f32x4 lo, f32x4 hi) {
    bf16x8 r;
    r[0] = (short)f2bf(lo[0]); r[1] = (short)f2bf(lo[1]);
    r[2] = (short)f2bf(lo[2]); r[3] = (short)f2bf(lo[3]);
    r[4] = (short)f2bf(hi[0]); r[5] = (short)f2bf(hi[1]);
    r[6] = (short)f2bf(hi[2]); r[7] = (short)f2bf(hi[3]);
    return r;
}

// ---------------------------------------------------------------------------
// Kernel 1: xwt = (X @ W1)^T bf16, tiled+swizzled for direct global_load_lds:
//   16B unit u = kc2*512 + ct*64 + c*4 + ku within each 16KB slab-pair,
//   STORED at position p = u ^ (c&7).  (R8/R9-proven layout.)
// ---------------------------------------------------------------------------
__global__ __launch_bounds__(256) void k_xw(const float* __restrict__ x,
                                            const float* __restrict__ W1,
                                            unsigned short* __restrict__ xwt) {
    __shared__ float xs[16][128];
    __shared__ unsigned short ts[16][136];
    const int t  = threadIdx.x;
    const int nb = blockIdx.x * 16;

    #pragma unroll
    for (int i = 0; i < 2; ++i) {
        int idx = t + i * 256;
        int n   = idx >> 5;
        int c4  = idx & 31;
        int gn  = nb + n; if (gn > N_NODES - 1) gn = N_NODES - 1;
        f32x4 v = *reinterpret_cast<const f32x4*>(x + (size_t)gn * F + c4 * 4);
        *reinterpret_cast<f32x4*>(&xs[n][c4 * 4]) = v;
    }
    __syncthreads();

    const int f  = t & 127;
    const int ng = t >> 7;
    float acc[8] = {0.f, 0.f, 0.f, 0.f, 0.f, 0.f, 0.f, 0.f};

    for (int c4 = 0; c4 < 32; ++c4) {
        float w0 = W1[(4 * c4 + 0) * F + f];
        float w1 = W1[(4 * c4 + 1) * F + f];
        float w2 = W1[(4 * c4 + 2) * F + f];
        float w3 = W1[(4 * c4 + 3) * F + f];
        #pragma unroll
        for (int i = 0; i < 8; ++i) {
            f32x4 xv = *reinterpret_cast<const f32x4*>(&xs[ng * 8 + i][c4 * 4]);
            acc[i] = fmaf(xv.x, w0, fmaf(xv.y, w1, fmaf(xv.z, w2, fmaf(xv.w, w3, acc[i]))));
        }
    }

    #pragma unroll
    for (int i = 0; i < 8; ++i) ts[ng * 8 + i][f] = f2bf(acc[i]);
    __syncthreads();

    {
        const int col = t >> 1, half = t & 1;
        s16x8 v8;
        #pragma unroll
        for (int i = 0; i < 8; ++i) {
            int n = half * 8 + i;
            v8[i] = (nb + n < N_NODES) ? (short)ts[n][col] : (short)0;
        }
        const int c  = col & 15, ct = col >> 4;
        const int kc = nb >> 5, khalf = (nb >> 4) & 1;
        const int ku = khalf * 2 + half;
        int upair = (kc & 1) * 512 + ct * 64 + c * 4 + ku;
        size_t off = (size_t)(kc >> 1) * 8192 + (size_t)(upair ^ (c & 7)) * 8;
        *reinterpret_cast<s16x8*>(xwt + off) = v8;
    }
}

// ---------------------------------------------------------------------------
// Kernel 2: partial GEMM, split-K (R9 skeleton + T4 counted-vmcnt pipeline).
// grid 1256 x 512 (mb = bid%157, split = bid/157). Block 64r x 128c x 1280k.
// B: gload_lds, TRIPLE buffer, staged 2 tiles ahead -> full-tile latency cover.
// A: 512B-per-row visits; load pair at even tile -> regs, vmcnt(2), ds_write
//    at odd tile into a 4-slot ring. Raw s_barrier + lgkmcnt(0); vmcnt never
//    drained to 0 in steady state (even: vmcnt(6), odd: vmcnt(2)).
// P partials in bf16 (halves P traffic).
// ---------------------------------------------------------------------------
#define GLOAD(gsrc, ldst) __builtin_amdgcn_global_load_lds(                      \
    (const __attribute__((address_space(1))) unsigned int*)(gsrc),               \
    (__attribute__((address_space(3))) unsigned int*)(ldst), 16, 0, 0)

#define MFMA_(a, b, c) __builtin_amdgcn_mfma_f32_16x16x32_bf16(a, b, c, 0, 0, 0)

#define WAITVM(N) asm volatile("s_waitcnt vmcnt(" #N ")" ::: "memory")
#define BAR() do { asm volatile("s_waitcnt lgkmcnt(0)" ::: "memory"); \
                   __builtin_amdgcn_s_barrier(); } while (0)

__global__ __launch_bounds__(512, 4) void k_gcn(const float* __restrict__ A,
                                                const unsigned short* __restrict__ xwt,
                                                unsigned short* __restrict__ P) {
    __shared__ __align__(16) unsigned char Bs[3][16384];   // 48 KB (triple)
    __shared__ __align__(16) unsigned char As[4][8192];    // 32 KB (ring-4)

    const int t    = threadIdx.x;
    const int w    = t >> 6;
    const int lane = t & 63;
    const int l16  = lane & 15;
    const int g    = lane >> 4;
    const int mq   = w >> 2;         // 0..1 : 32-row half
    const int cq   = w & 3;          // 0..3 : 32-col quarter
    const int mb    = blockIdx.x % MBLK;
    const int split = blockIdx.x / MBLK;
    const int rbase = mb * BM;
    const int k0    = split * KSPLIT;

    // ---- A staging: thread t -> row (t>>3), 64B chunk (t&7) of 512B pair ----
    const int sr = t >> 3, c8 = t & 7;
    int arow = rbase + sr; if (arow > N_NODES - 1) arow = N_NODES - 1;
    const size_t abase = (size_t)arow * N_NODES + k0 + c8 * 16;
    const size_t lim4  = (size_t)N_NODES * N_NODES - 4;

    const unsigned char* const xb  = reinterpret_cast<const unsigned char*>(xwt);
    unsigned char* const AsB = &As[0][0];
    unsigned char* const BsB = &Bs[0][0];

    // ---- fragment read byte offsets (R9 verbatim, within one slot/buffer) ----
    int ar00, ar01, ar10, ar11;
    {
        int r0 = mq * 32 + l16, r1 = mq * 32 + 16 + l16;
        ar00 = r0 * 128 + ((0 * 4 + g) ^ (r0 & 7)) * 16;
        ar01 = r0 * 128 + ((1 * 4 + g) ^ (r0 & 7)) * 16;
        ar10 = r1 * 128 + ((0 * 4 + g) ^ (r1 & 7)) * 16;
        ar11 = r1 * 128 + ((1 * 4 + g) ^ (r1 & 7)) * 16;
    }
    int br00, br01, br10, br11;
    {
        int m = l16 & 7;
        br00 = ((0 * 512 + (cq * 2 + 0) * 64 + l16 * 4 + g) ^ m) * 16;
        br01 = ((1 * 512 + (cq * 2 + 0) * 64 + l16 * 4 + g) ^ m) * 16;
        br10 = ((0 * 512 + (cq * 2 + 1) * 64 + l16 * 4 + g) ^ m) * 16;
        br11 = ((1 * 512 + (cq * 2 + 1) * 64 + l16 * 4 + g) ^ m) * 16;
    }

    f32x4 acc00 = {0.f, 0.f, 0.f, 0.f}, acc01 = acc00, acc10 = acc00, acc11 = acc00;
    f32x4 la0, la1, la2, la3;   // 64B A stage (one 512B-per-row pair)

#define LOADA(pair) do {                                                         \
    size_t _b = abase + (size_t)(pair) * 128;                                    \
    size_t _o0 = _b;      if (_o0 > lim4) _o0 = lim4;                            \
    size_t _o1 = _b + 4;  if (_o1 > lim4) _o1 = lim4;                            \
    size_t _o2 = _b + 8;  if (_o2 > lim4) _o2 = lim4;                            \
    size_t _o3 = _b + 12; if (_o3 > lim4) _o3 = lim4;                            \
    la0 = __builtin_nontemporal_load(reinterpret_cast<const f32x4*>(A + _o0));   \
    la1 = __builtin_nontemporal_load(reinterpret_cast<const f32x4*>(A + _o1));   \
    la2 = __builtin_nontemporal_load(reinterpret_cast<const f32x4*>(A + _o2));   \
    la3 = __builtin_nontemporal_load(reinterpret_cast<const f32x4*>(A + _o3));   \
} while (0)

    // thread's 64B -> 2 16B bf16 units; c8<4 -> first tile of pair, else second
#define WRITEA(slotE, slotO) do {                                                \
    int _slot = (c8 < 4) ? (slotE) : (slotO);                                    \
    int _u0   = (c8 & 3) * 2;                                                    \
    unsigned char* _r = AsB + _slot * 8192 + sr * 128;                           \
    *reinterpret_cast<bf16x8*>(_r + (((_u0    ) ^ (sr & 7)) * 16)) = pack8(la0, la1); \
    *reinterpret_cast<bf16x8*>(_r + (((_u0 + 1) ^ (sr & 7)) * 16)) = pack8(la2, la3); \
} while (0)

#define STAGEB(tile, buf) do {                                                   \
    const unsigned char* _cb = xb + (size_t)(split * 40 + 2 * (tile)) * 8192;    \
    unsigned char* _bd = BsB + (buf) * 16384;                                    \
    GLOAD(_cb + (w * 2 + 0) * 1024 + lane * 16, _bd + (w * 2 + 0) * 1024);       \
    GLOAD(_cb + (w * 2 + 1) * 1024 + lane * 16, _bd + (w * 2 + 1) * 1024);       \
} while (0)

#define COMPUTE(slot, buf) do {                                                  \
    const unsigned char* _as = AsB + (slot) * 8192;                              \
    const unsigned char* _bs = BsB + (buf) * 16384;                              \
    bf16x8 af00 = *reinterpret_cast<const bf16x8*>(_as + ar00);                  \
    bf16x8 af01 = *reinterpret_cast<const bf16x8*>(_as + ar01);                  \
    bf16x8 af10 = *reinterpret_cast<const bf16x8*>(_as + ar10);                  \
    bf16x8 af11 = *reinterpret_cast<const bf16x8*>(_as + ar11);                  \
    bf16x8 bf00 = *reinterpret_cast<const bf16x8*>(_bs + br00);                  \
    bf16x8 bf01 = *reinterpret_cast<const bf16x8*>(_bs + br01);                  \
    bf16x8 bf10 = *reinterpret_cast<const bf16x8*>(_bs + br10);                  \
    bf16x8 bf11 = *reinterpret_cast<const bf16x8*>(_bs + br11);                  \
    acc00 = MFMA_(af00, bf00, acc00); acc00 = MFMA_(af01, bf01, acc00);          \
    acc01 = MFMA_(af00, bf10, acc01); acc01 = MFMA_(af01, bf11, acc01);          \
    acc10 = MFMA_(af10, bf00, acc10); acc10 = MFMA_(af11, bf01, acc10);          \
    acc11 = MFMA_(af10, bf10, acc11); acc11 = MFMA_(af11, bf11, acc11);          \
} while (0)

    // ---- prologue ----
    LOADA(0);                 // 4 vm
    STAGEB(0, 0);             // 2 vm
    STAGEB(1, 1);             // 2 vm
    WAITVM(2);                // LOADA(0)+STAGEB(0) done; STAGEB(1) in flight
    WRITEA(0, 1);             // pair 0 -> slots 0,1
    LOADA(1);                 // out = STB(1)2 + LA(1)4 = 6
    BAR();

    // ---- main loop: pairs p = 0..8 (tiles 0..17) ----
    int bufE = 0;             // (2p) % 3
    for (int p = 0; p < 9; ++p) {
        const int te = 2 * p, to = 2 * p + 1;
        const int slotE = te & 3, slotO = to & 3;
        const int bufO  = (bufE + 1 == 3) ? 0 : bufE + 1;
        const int bufE2 = (bufO + 1 == 3) ? 0 : bufO + 1;   // (te+2)%3
        // even tile
        STAGEB(te + 2, bufE2);
        COMPUTE(slotE, bufE);
        WAITVM(6);            // STB(te+1) done; leaves LA(p+1)4 + STB(te+2)2
        BAR();
        // odd tile
        STAGEB(to + 2, bufE); // (to+2)%3 == bufE
        COMPUTE(slotO, bufO);
        WAITVM(2);            // LA(p+1) + STB(to+1) done; leaves STB(to+2)
        WRITEA((te + 2) & 3, (to + 2) & 3);   // pair p+1
        if (p < 8) LOADA(p + 2);
        BAR();
        bufE = bufE2;
    }

    // ---- tail: pair 9 (tiles 18,19); entering outstanding = STB(19) only ----
    COMPUTE(18 & 3, 0);       // 18%3 = 0
    WAITVM(0);                // STB(19) done
    BAR();
    COMPUTE(19 & 3, 1);       // 19%3 = 1

    // ---- write bf16 partials: row = rbase+mq*32+g*4+e(+16), col = cq*32+l16(+16)
    {
        unsigned short* Pp = P + ((size_t)split * PROWS + rbase) * F;
        #pragma unroll
        for (int e = 0; e < 4; ++e) {
            Pp[(size_t)(mq * 32 +  0 + g * 4 + e) * F + cq * 32 +      l16] = f2bf(acc00[e]);
            Pp[(size_t)(mq * 32 +  0 + g * 4 + e) * F + cq * 32 + 16 + l16] = f2bf(acc01[e]);
            Pp[(size_t)(mq * 32 + 16 + g * 4 + e) * F + cq * 32 +      l16] = f2bf(acc10[e]);
            Pp[(size_t)(mq * 32 + 16 + g * 4 + e) * F + cq * 32 + 16 + l16] = f2bf(acc11[e]);
        }
    }
#undef LOADA
#undef WRITEA
#undef STAGEB
#undef COMPUTE
}

// ---------------------------------------------------------------------------
// Kernel 3: out[r] = relu(sum_s bf2f(P[s][r][:]) + b1) . W2 + b2. grid 5000x256.
// ---------------------------------------------------------------------------
__global__ __launch_bounds__(256) void k_red(const unsigned short* __restrict__ P,
                                             const float* __restrict__ b1,
                                             const float* __restrict__ W2,
                                             const float* __restrict__ b2,
                                             float* __restrict__ out) {
    __shared__ float sred[4];
    const int t   = threadIdx.x;
    const int row = blockIdx.x * 2 + (t >> 7);
    const int c   = t & 127;

    float v = 0.f;
    #pragma unroll
    for (int s = 0; s < SPLITS; ++s) {
        unsigned u = P[((size_t)s * PROWS + row) * F + c];
        v += __builtin_bit_cast(float, u << 16);
    }
    v = fmaxf(v + b1[c], 0.f) * W2[c];

    v += __shfl_xor(v, 1);
    v += __shfl_xor(v, 2);
    v += __shfl_xor(v, 4);
    v += __shfl_xor(v, 8);
    v += __shfl_xor(v, 16);
    v += __shfl_xor(v, 32);
    if ((t & 63) == 0) sred[t >> 6] = v;
    __syncthreads();
    if (t < 2) out[blockIdx.x * 2 + t] = sred[t * 2] + sred[t * 2 + 1] + b2[0];
}

extern "C" void kernel_launch(void* const* d_in, const int* in_sizes, int n_in,
                              void* d_out, int out_size, void* d_ws, size_t ws_size,
                              hipStream_t stream) {
    const float* x  = (const float*)d_in[0];
    const float* a  = (const float*)d_in[1];
    const float* W1 = (const float*)d_in[2];
    const float* b1 = (const float*)d_in[3];
    const float* W2 = (const float*)d_in[4];
    const float* b2 = (const float*)d_in[5];
    float* out = (float*)d_out;

    unsigned short* xwt = (unsigned short*)d_ws;                    // 2.62 MB tiled
    unsigned short* P = (unsigned short*)((char*)d_ws + (size_t)(16 << 20)); // bf16 partials

    k_xw<<<640, 256, 0, stream>>>(x, W1, xwt);
    k_gcn<<<MBLK * SPLITS, 512, 0, stream>>>(a, xwt, P);
    k_red<<<5000, 256, 0, stream>>>(P, b1, W2, b2, out);
}

// Round 14
// 184.115 us; speedup vs baseline: 1.6873x; 1.0451x over previous
//
#include <hip/hip_runtime.h>
#include <hip/hip_bf16.h>

#define N_NODES 10000
#define KP      10240   // K padded; xwt pad slabs are ZERO
#define F       128
#define SPLITS  8
#define KSPLIT  1280    // KP / SPLITS
#define BK      64
#define TPS     20      // tiles per split (= 5 quads)
#define BM      64
#define MBLK    157     // ceil(10000/64)
#define PROWS   10048   // MBLK*64

typedef float  f32x4  __attribute__((ext_vector_type(4)));
typedef short  bf16x8 __attribute__((ext_vector_type(8)));
typedef short  s16x8  __attribute__((ext_vector_type(8)));

static __device__ __forceinline__ unsigned short f2bf(float f) {
    unsigned u = __builtin_bit_cast(unsigned, f);
    u += 0x7FFFu + ((u >> 16) & 1u);
    return (unsigned short)(u >> 16);
}

static __device__ __forceinline__ bf16x8 pack8(f32x4 lo, f32x4 hi) {
    bf16x8 r;
    r[0] = (short)f2bf(lo[0]); r[1] = (short)f2bf(lo[1]);
    r[2] = (short)f2bf(lo[2]); r[3] = (short)f2bf(lo[3]);
    r[4] = (short)f2bf(hi[0]); r[5] = (short)f2bf(hi[1]);
    r[6] = (short)f2bf(hi[2]); r[7] = (short)f2bf(hi[3]);
    return r;
}

// ---------------------------------------------------------------------------
// Kernel 1: xwt = (X @ W1)^T bf16, tiled+swizzled for direct global_load_lds:
//   16B unit u = kc2*512 + ct*64 + c*4 + ku within each 16KB slab-pair,
//   STORED at position p = u ^ (c&7).  (R8/R9-proven layout.)
// ---------------------------------------------------------------------------
__global__ __launch_bounds__(256) void k_xw(const float* __restrict__ x,
                                            const float* __restrict__ W1,
                                            unsigned short* __restrict__ xwt) {
    __shared__ float xs[16][128];
    __shared__ unsigned short ts[16][136];
    const int t  = threadIdx.x;
    const int nb = blockIdx.x * 16;

    #pragma unroll
    for (int i = 0; i < 2; ++i) {
        int idx = t + i * 256;
        int n   = idx >> 5;
        int c4  = idx & 31;
        int gn  = nb + n; if (gn > N_NODES - 1) gn = N_NODES - 1;
        f32x4 v = *reinterpret_cast<const f32x4*>(x + (size_t)gn * F + c4 * 4);
        *reinterpret_cast<f32x4*>(&xs[n][c4 * 4]) = v;
    }
    __syncthreads();

    const int f  = t & 127;
    const int ng = t >> 7;
    float acc[8] = {0.f, 0.f, 0.f, 0.f, 0.f, 0.f, 0.f, 0.f};

    for (int c4 = 0; c4 < 32; ++c4) {
        float w0 = W1[(4 * c4 + 0) * F + f];
        float w1 = W1[(4 * c4 + 1) * F + f];
        float w2 = W1[(4 * c4 + 2) * F + f];
        float w3 = W1[(4 * c4 + 3) * F + f];
        #pragma unroll
        for (int i = 0; i < 8; ++i) {
            f32x4 xv = *reinterpret_cast<const f32x4*>(&xs[ng * 8 + i][c4 * 4]);
            acc[i] = fmaf(xv.x, w0, fmaf(xv.y, w1, fmaf(xv.z, w2, fmaf(xv.w, w3, acc[i]))));
        }
    }

    #pragma unroll
    for (int i = 0; i < 8; ++i) ts[ng * 8 + i][f] = f2bf(acc[i]);
    __syncthreads();

    {
        const int col = t >> 1, half = t & 1;
        s16x8 v8;
        #pragma unroll
        for (int i = 0; i < 8; ++i) {
            int n = half * 8 + i;
            v8[i] = (nb + n < N_NODES) ? (short)ts[n][col] : (short)0;
        }
        const int c  = col & 15, ct = col >> 4;
        const int kc = nb >> 5, khalf = (nb >> 4) & 1;
        const int ku = khalf * 2 + half;
        int upair = (kc & 1) * 512 + ct * 64 + c * 4 + ku;
        size_t off = (size_t)(kc >> 1) * 8192 + (size_t)(upair ^ (c & 7)) * 8;
        *reinterpret_cast<s16x8*>(xwt + off) = v8;
    }
}

// ---------------------------------------------------------------------------
// Kernel 2: partial GEMM, split-K (R9 schedule verbatim; byte-level changes):
// grid 1256 x 512 (mb = bid%157, split = bid/157). Block 64r x 128c x 1280k.
// A: 1KB-per-row DRAM visits (4 tiles per LOADA), plain (non-nt) loads,
//    ALL threads write in every WRITEA (thread's 128B -> tile c8>>1),
//    ring-6 LDS slots. B: gload_lds double-buffer. Plain __syncthreads/tile.
// P partials in bf16.
// ---------------------------------------------------------------------------
#define GLOAD(gsrc, ldst) __builtin_amdgcn_global_load_lds(                      \
    (const __attribute__((address_space(1))) unsigned int*)(gsrc),               \
    (__attribute__((address_space(3))) unsigned int*)(ldst), 16, 0, 0)

#define MFMA_(a, b, c) __builtin_amdgcn_mfma_f32_16x16x32_bf16(a, b, c, 0, 0, 0)

__global__ __launch_bounds__(512, 4) void k_gcn(const float* __restrict__ A,
                                                const unsigned short* __restrict__ xwt,
                                                unsigned short* __restrict__ P) {
    __shared__ __align__(16) unsigned char Bs[2][16384];   // 32 KB
    __shared__ __align__(16) unsigned char As[6][8192];    // 48 KB ring-6

    const int t    = threadIdx.x;
    const int w    = t >> 6;
    const int lane = t & 63;
    const int l16  = lane & 15;
    const int g    = lane >> 4;
    const int mq   = w >> 2;         // 0..1 : 32-row half
    const int cq   = w & 3;          // 0..3 : 32-col quarter
    const int mb    = blockIdx.x % MBLK;
    const int split = blockIdx.x / MBLK;
    const int rbase = mb * BM;
    const int k0    = split * KSPLIT;

    // ---- A staging: thread t -> row (t>>3), 128B chunk (t&7) of 1KB quad ----
    const int sr = t >> 3, c8 = t & 7;
    int arow = rbase + sr; if (arow > N_NODES - 1) arow = N_NODES - 1;
    const size_t abase = (size_t)arow * N_NODES + k0 + c8 * 32;
    const size_t lim4  = (size_t)N_NODES * N_NODES - 4;

    const unsigned char* const xb  = reinterpret_cast<const unsigned char*>(xwt);
    unsigned char* const AsB = &As[0][0];

    // ---- fragment read byte offsets (R9 verbatim) ----
    int ar00, ar01, ar10, ar11;
    {
        int r0 = mq * 32 + l16, r1 = mq * 32 + 16 + l16;
        ar00 = r0 * 128 + ((0 * 4 + g) ^ (r0 & 7)) * 16;
        ar01 = r0 * 128 + ((1 * 4 + g) ^ (r0 & 7)) * 16;
        ar10 = r1 * 128 + ((0 * 4 + g) ^ (r1 & 7)) * 16;
        ar11 = r1 * 128 + ((1 * 4 + g) ^ (r1 & 7)) * 16;
    }
    int br00, br01, br10, br11;
    {
        int m = l16 & 7;
        br00 = ((0 * 512 + (cq * 2 + 0) * 64 + l16 * 4 + g) ^ m) * 16;
        br01 = ((1 * 512 + (cq * 2 + 0) * 64 + l16 * 4 + g) ^ m) * 16;
        br10 = ((0 * 512 + (cq * 2 + 1) * 64 + l16 * 4 + g) ^ m) * 16;
        br11 = ((1 * 512 + (cq * 2 + 1) * 64 + l16 * 4 + g) ^ m) * 16;
    }

    f32x4 acc00 = {0.f, 0.f, 0.f, 0.f}, acc01 = acc00, acc10 = acc00, acc11 = acc00;
    f32x4 la0, la1, la2, la3, la4, la5, la6, la7;   // 128B/thread = 1KB/row quad

    // quad q = tiles 4q..4q+3; thread's 32 floats: [c8*32, c8*32+32) of the 1KB
#define LOADA(q) do {                                                            \
    size_t _b = abase + (size_t)(q) * 256;                                       \
    size_t _o;                                                                   \
    _o = _b;      if (_o > lim4) _o = lim4;  la0 = *reinterpret_cast<const f32x4*>(A + _o); \
    _o = _b + 4;  if (_o > lim4) _o = lim4;  la1 = *reinterpret_cast<const f32x4*>(A + _o); \
    _o = _b + 8;  if (_o > lim4) _o = lim4;  la2 = *reinterpret_cast<const f32x4*>(A + _o); \
    _o = _b + 12; if (_o > lim4) _o = lim4;  la3 = *reinterpret_cast<const f32x4*>(A + _o); \
    _o = _b + 16; if (_o > lim4) _o = lim4;  la4 = *reinterpret_cast<const f32x4*>(A + _o); \
    _o = _b + 20; if (_o > lim4) _o = lim4;  la5 = *reinterpret_cast<const f32x4*>(A + _o); \
    _o = _b + 24; if (_o > lim4) _o = lim4;  la6 = *reinterpret_cast<const f32x4*>(A + _o); \
    _o = _b + 28; if (_o > lim4) _o = lim4;  la7 = *reinterpret_cast<const f32x4*>(A + _o); \
} while (0)

    // write quad whose FIRST tile maps to ring slot `base`; thread's tile = c8>>1
#define WRITEA(base) do {                                                        \
    int _slot = ((base) + (c8 >> 1)) % 6;                                        \
    int _u0   = (c8 & 1) * 4;                                                    \
    unsigned char* _r = AsB + _slot * 8192 + sr * 128;                           \
    *reinterpret_cast<bf16x8*>(_r + (((_u0 + 0) ^ (sr & 7)) * 16)) = pack8(la0, la1); \
    *reinterpret_cast<bf16x8*>(_r + (((_u0 + 1) ^ (sr & 7)) * 16)) = pack8(la2, la3); \
    *reinterpret_cast<bf16x8*>(_r + (((_u0 + 2) ^ (sr & 7)) * 16)) = pack8(la4, la5); \
    *reinterpret_cast<bf16x8*>(_r + (((_u0 + 3) ^ (sr & 7)) * 16)) = pack8(la6, la7); \
} while (0)

#define STAGEB(tile, buf) do {                                                   \
    const unsigned char* _cb = xb + (size_t)(split * 40 + 2 * (tile)) * 8192;    \
    GLOAD(_cb + (w * 2 + 0) * 1024 + lane * 16, &Bs[buf][(w * 2 + 0) * 1024]);   \
    GLOAD(_cb + (w * 2 + 1) * 1024 + lane * 16, &Bs[buf][(w * 2 + 1) * 1024]);   \
} while (0)

#define COMPUTE(slot, buf) do {                                                  \
    const unsigned char* _as = AsB + (slot) * 8192;                              \
    bf16x8 af00 = *reinterpret_cast<const bf16x8*>(_as + ar00);                  \
    bf16x8 af01 = *reinterpret_cast<const bf16x8*>(_as + ar01);                  \
    bf16x8 af10 = *reinterpret_cast<const bf16x8*>(_as + ar10);                  \
    bf16x8 af11 = *reinterpret_cast<const bf16x8*>(_as + ar11);                  \
    bf16x8 bf00 = *reinterpret_cast<const bf16x8*>(&Bs[buf][br00]);              \
    bf16x8 bf01 = *reinterpret_cast<const bf16x8*>(&Bs[buf][br01]);              \
    bf16x8 bf10 = *reinterpret_cast<const bf16x8*>(&Bs[buf][br10]);              \
    bf16x8 bf11 = *reinterpret_cast<const bf16x8*>(&Bs[buf][br11]);              \
    acc00 = MFMA_(af00, bf00, acc00); acc00 = MFMA_(af01, bf01, acc00);          \
    acc01 = MFMA_(af00, bf10, acc01); acc01 = MFMA_(af01, bf11, acc01);          \
    acc10 = MFMA_(af10, bf00, acc10); acc10 = MFMA_(af11, bf01, acc10);          \
    acc11 = MFMA_(af10, bf10, acc11); acc11 = MFMA_(af11, bf11, acc11);          \
} while (0)

    // ---- prologue: quad0 -> slots 0..3; quad1 parked in regs; B tile 0 ----
    LOADA(0);
    STAGEB(0, 0);
    WRITEA(0);         // compiler waits LOADA(0)
    LOADA(1);
    __syncthreads();

    // ---- main loop (R9 greedy schedule, drain barrier per tile) ----
    // tile t computes slot t%6; at t = 2,6,10,14: write parked quad (t+2)/4
    // into slots (t+2)%6.., then (t <= 10) load quad (t+6)/4.
    for (int tile = 0; tile < TPS; ++tile) {
        if (tile + 1 < TPS) STAGEB(tile + 1, (tile + 1) & 1);
        if ((tile & 3) == 2 && tile + 2 < TPS) {
            WRITEA((tile + 2) % 6);
            if (tile <= 10) LOADA((tile + 6) >> 2);
        }
        COMPUTE(tile % 6, tile & 1);
        __syncthreads();
    }

    // ---- write bf16 partials ----
    {
        unsigned short* Pp = P + ((size_t)split * PROWS + rbase) * F;
        #pragma unroll
        for (int e = 0; e < 4; ++e) {
            Pp[(size_t)(mq * 32 +  0 + g * 4 + e) * F + cq * 32 +      l16] = f2bf(acc00[e]);
            Pp[(size_t)(mq * 32 +  0 + g * 4 + e) * F + cq * 32 + 16 + l16] = f2bf(acc01[e]);
            Pp[(size_t)(mq * 32 + 16 + g * 4 + e) * F + cq * 32 +      l16] = f2bf(acc10[e]);
            Pp[(size_t)(mq * 32 + 16 + g * 4 + e) * F + cq * 32 + 16 + l16] = f2bf(acc11[e]);
        }
    }
#undef LOADA
#undef WRITEA
#undef STAGEB
#undef COMPUTE
}

// ---------------------------------------------------------------------------
// Kernel 3: out[r] = relu(sum_s bf2f(P[s][r][:]) + b1) . W2 + b2. grid 5000x256.
// ---------------------------------------------------------------------------
__global__ __launch_bounds__(256) void k_red(const unsigned short* __restrict__ P,
                                             const float* __restrict__ b1,
                                             const float* __restrict__ W2,
                                             const float* __restrict__ b2,
                                             float* __restrict__ out) {
    __shared__ float sred[4];
    const int t   = threadIdx.x;
    const int row = blockIdx.x * 2 + (t >> 7);
    const int c   = t & 127;

    float v = 0.f;
    #pragma unroll
    for (int s = 0; s < SPLITS; ++s) {
        unsigned u = P[((size_t)s * PROWS + row) * F + c];
        v += __builtin_bit_cast(float, u << 16);
    }
    v = fmaxf(v + b1[c], 0.f) * W2[c];

    v += __shfl_xor(v, 1);
    v += __shfl_xor(v, 2);
    v += __shfl_xor(v, 4);
    v += __shfl_xor(v, 8);
    v += __shfl_xor(v, 16);
    v += __shfl_xor(v, 32);
    if ((t & 63) == 0) sred[t >> 6] = v;
    __syncthreads();
    if (t < 2) out[blockIdx.x * 2 + t] = sred[t * 2] + sred[t * 2 + 1] + b2[0];
}

extern "C" void kernel_launch(void* const* d_in, const int* in_sizes, int n_in,
                              void* d_out, int out_size, void* d_ws, size_t ws_size,
                              hipStream_t stream) {
    const float* x  = (const float*)d_in[0];
    const float* a  = (const float*)d_in[1];
    const float* W1 = (const float*)d_in[2];
    const float* b1 = (const float*)d_in[3];
    const float* W2 = (const float*)d_in[4];
    const float* b2 = (const float*)d_in[5];
    float* out = (float*)d_out;

    unsigned short* xwt = (unsigned short*)d_ws;                    // 2.62 MB tiled
    unsigned short* P = (unsigned short*)((char*)d_ws + (size_t)(16 << 20)); // bf16 partials

    k_xw<<<640, 256, 0, stream>>>(x, W1, xwt);
    k_gcn<<<MBLK * SPLITS, 512, 0, stream>>>(a, xwt, P);
    k_red<<<5000, 256, 0, stream>>>(P, b1, W2, b2, out);
}

// Round 15
// 121.691 us; speedup vs baseline: 2.5529x; 1.5130x over previous
//
#include <hip/hip_runtime.h>
#include <hip/hip_bf16.h>

#define N_NODES 10000
#define KP      10240   // K padded; xwt pad slabs are ZERO
#define F       128
#define SPLITS  8
#define KSPLIT  1280    // KP / SPLITS
#define BK      64
#define TPS     20      // tiles per split (= 5 quads)
#define BM      64
#define MBLK    157     // ceil(10000/64)
#define PROWS   10048   // MBLK*64
#define ALIM    (100000000u - 4u)   // N*N - 4

typedef float  f32x4  __attribute__((ext_vector_type(4)));
typedef short  bf16x8 __attribute__((ext_vector_type(8)));
typedef short  s16x8  __attribute__((ext_vector_type(8)));
typedef short  s16x4  __attribute__((ext_vector_type(4)));

static __device__ __forceinline__ unsigned short f2bf(float f) {
    unsigned u = __builtin_bit_cast(unsigned, f);
    u += 0x7FFFu + ((u >> 16) & 1u);
    return (unsigned short)(u >> 16);
}

static __device__ __forceinline__ s16x4 pack4(f32x4 v) {
    s16x4 r;
    r[0] = (short)f2bf(v[0]); r[1] = (short)f2bf(v[1]);
    r[2] = (short)f2bf(v[2]); r[3] = (short)f2bf(v[3]);
    return r;
}

// ---------------------------------------------------------------------------
// Kernel 1: xwt = (X @ W1)^T bf16, tiled+swizzled for direct global_load_lds:
//   16B unit u = kc2*512 + ct*64 + c*4 + ku within each 16KB slab-pair,
//   STORED at position p = u ^ (c&7).  (R8/R9-proven layout.)
// ---------------------------------------------------------------------------
__global__ __launch_bounds__(256) void k_xw(const float* __restrict__ x,
                                            const float* __restrict__ W1,
                                            unsigned short* __restrict__ xwt) {
    __shared__ float xs[16][128];
    __shared__ unsigned short ts[16][136];
    const int t  = threadIdx.x;
    const int nb = blockIdx.x * 16;

    #pragma unroll
    for (int i = 0; i < 2; ++i) {
        int idx = t + i * 256;
        int n   = idx >> 5;
        int c4  = idx & 31;
        int gn  = nb + n; if (gn > N_NODES - 1) gn = N_NODES - 1;
        f32x4 v = *reinterpret_cast<const f32x4*>(x + (size_t)gn * F + c4 * 4);
        *reinterpret_cast<f32x4*>(&xs[n][c4 * 4]) = v;
    }
    __syncthreads();

    const int f  = t & 127;
    const int ng = t >> 7;
    float acc[8] = {0.f, 0.f, 0.f, 0.f, 0.f, 0.f, 0.f, 0.f};

    for (int c4 = 0; c4 < 32; ++c4) {
        float w0 = W1[(4 * c4 + 0) * F + f];
        float w1 = W1[(4 * c4 + 1) * F + f];
        float w2 = W1[(4 * c4 + 2) * F + f];
        float w3 = W1[(4 * c4 + 3) * F + f];
        #pragma unroll
        for (int i = 0; i < 8; ++i) {
            f32x4 xv = *reinterpret_cast<const f32x4*>(&xs[ng * 8 + i][c4 * 4]);
            acc[i] = fmaf(xv.x, w0, fmaf(xv.y, w1, fmaf(xv.z, w2, fmaf(xv.w, w3, acc[i]))));
        }
    }

    #pragma unroll
    for (int i = 0; i < 8; ++i) ts[ng * 8 + i][f] = f2bf(acc[i]);
    __syncthreads();

    {
        const int col = t >> 1, half = t & 1;
        s16x8 v8;
        #pragma unroll
        for (int i = 0; i < 8; ++i) {
            int n = half * 8 + i;
            v8[i] = (nb + n < N_NODES) ? (short)ts[n][col] : (short)0;
        }
        const int c  = col & 15, ct = col >> 4;
        const int kc = nb >> 5, khalf = (nb >> 4) & 1;
        const int ku = khalf * 2 + half;
        int upair = (kc & 1) * 512 + ct * 64 + c * 4 + ku;
        size_t off = (size_t)(kc >> 1) * 8192 + (size_t)(upair ^ (c & 7)) * 8;
        *reinterpret_cast<s16x8*>(xwt + off) = v8;
    }
}

// ---------------------------------------------------------------------------
// Kernel 2: partial GEMM, split-K (R9 schedule verbatim). Change vs R9:
// A-loads are ONE FULL 1KB ROW-CHUNK PER INSTRUCTION (64 lanes x 16B contig,
// row = w*8+j chosen per instruction j=0..7) -> true 1KB DRAM bursts.
// Quad (4 tiles) per LOADA into la0..7; ds_write_b64 into ring-6 A slots.
// B: gload_lds double-buffer (unchanged). Plain __syncthreads per tile.
// P partials bf16.
// ---------------------------------------------------------------------------
#define GLOAD(gsrc, ldst) __builtin_amdgcn_global_load_lds(                      \
    (const __attribute__((address_space(1))) unsigned int*)(gsrc),               \
    (__attribute__((address_space(3))) unsigned int*)(ldst), 16, 0, 0)

#define MFMA_(a, b, c) __builtin_amdgcn_mfma_f32_16x16x32_bf16(a, b, c, 0, 0, 0)

__global__ __launch_bounds__(512, 4) void k_gcn(const float* __restrict__ A,
                                                const unsigned short* __restrict__ xwt,
                                                unsigned short* __restrict__ P) {
    __shared__ __align__(16) unsigned char Bs[2][16384];   // 32 KB
    __shared__ __align__(16) unsigned char As[6][8192];    // 48 KB ring-6

    const int t    = threadIdx.x;
    const int w    = t >> 6;
    const int lane = t & 63;
    const int l16  = lane & 15;
    const int g    = lane >> 4;
    const int mq   = w >> 2;         // 0..1 : 32-row half
    const int cq   = w & 3;          // 0..3 : 32-col quarter
    const int mb    = blockIdx.x % MBLK;
    const int split = blockIdx.x / MBLK;
    const int rbase = mb * BM;
    const int k0    = split * KSPLIT;

    // ---- A staging (per-instruction rows): wave w instr j -> row w*8+j ----
    // flat uint base per j (row clamped to 9999); lane adds l*4 within 1KB chunk
    unsigned arb[8];
    #pragma unroll
    for (int j = 0; j < 8; ++j) {
        int r = rbase + w * 8 + j; if (r > N_NODES - 1) r = N_NODES - 1;
        arb[j] = (unsigned)r * (unsigned)N_NODES + (unsigned)k0;
    }
    const unsigned lq = (unsigned)(lane << 2);   // lane float offset in chunk

    // ds_write addressing: slot_sel = lane>>4 (tile within quad),
    // unit-byte = ((lane>>1)&7)<<4 XOR (j<<4), half-byte = (lane&1)*8
    const int asel  = lane >> 4;
    const int aub   = ((lane >> 1) & 7) << 4;
    const int ahalf = (lane & 1) * 8;
    const int awrow = w * 8;                     // + j gives local row

    const unsigned char* const xb  = reinterpret_cast<const unsigned char*>(xwt);
    unsigned char* const AsB = &As[0][0];

    // ---- fragment read byte offsets (R9 verbatim) ----
    int ar00, ar01, ar10, ar11;
    {
        int r0 = mq * 32 + l16, r1 = mq * 32 + 16 + l16;
        ar00 = r0 * 128 + ((0 * 4 + g) ^ (r0 & 7)) * 16;
        ar01 = r0 * 128 + ((1 * 4 + g) ^ (r0 & 7)) * 16;
        ar10 = r1 * 128 + ((0 * 4 + g) ^ (r1 & 7)) * 16;
        ar11 = r1 * 128 + ((1 * 4 + g) ^ (r1 & 7)) * 16;
    }
    int br00, br01, br10, br11;
    {
        int m = l16 & 7;
        br00 = ((0 * 512 + (cq * 2 + 0) * 64 + l16 * 4 + g) ^ m) * 16;
        br01 = ((1 * 512 + (cq * 2 + 0) * 64 + l16 * 4 + g) ^ m) * 16;
        br10 = ((0 * 512 + (cq * 2 + 1) * 64 + l16 * 4 + g) ^ m) * 16;
        br11 = ((1 * 512 + (cq * 2 + 1) * 64 + l16 * 4 + g) ^ m) * 16;
    }

    f32x4 acc00 = {0.f, 0.f, 0.f, 0.f}, acc01 = acc00, acc10 = acc00, acc11 = acc00;
    f32x4 la0, la1, la2, la3, la4, la5, la6, la7;   // 8 x 1KB-row-chunk loads

#define LD1(reg, j, q) do {                                                      \
    unsigned _o = arb[j] + (unsigned)(q) * 256u + lq;                            \
    if (_o > ALIM) _o = ALIM;                                                    \
    reg = __builtin_nontemporal_load(reinterpret_cast<const f32x4*>(A + _o));    \
} while (0)

#define LOADA(q) do {                                                            \
    LD1(la0, 0, q); LD1(la1, 1, q); LD1(la2, 2, q); LD1(la3, 3, q);              \
    LD1(la4, 4, q); LD1(la5, 5, q); LD1(la6, 6, q); LD1(la7, 7, q);              \
} while (0)

#define WR1(reg, j, s) do {                                                      \
    unsigned char* _p = AsB + (s) * 8192 + (awrow + (j)) * 128                   \
                      + (aub ^ ((j) << 4)) + ahalf;                              \
    *reinterpret_cast<s16x4*>(_p) = pack4(reg);                                  \
} while (0)

    // write quad whose first tile maps to ring slot `base`; lane's tile = asel
#define WRITEA(base) do {                                                        \
    int _s = (base) + asel; if (_s >= 6) _s -= 6;                                \
    WR1(la0, 0, _s); WR1(la1, 1, _s); WR1(la2, 2, _s); WR1(la3, 3, _s);          \
    WR1(la4, 4, _s); WR1(la5, 5, _s); WR1(la6, 6, _s); WR1(la7, 7, _s);          \
} while (0)

#define STAGEB(tile, buf) do {                                                   \
    const unsigned char* _cb = xb + (size_t)(split * 40 + 2 * (tile)) * 8192;    \
    GLOAD(_cb + (w * 2 + 0) * 1024 + lane * 16, &Bs[buf][(w * 2 + 0) * 1024]);   \
    GLOAD(_cb + (w * 2 + 1) * 1024 + lane * 16, &Bs[buf][(w * 2 + 1) * 1024]);   \
} while (0)

#define COMPUTE(slot, buf) do {                                                  \
    const unsigned char* _as = AsB + (slot) * 8192;                              \
    bf16x8 af00 = *reinterpret_cast<const bf16x8*>(_as + ar00);                  \
    bf16x8 af01 = *reinterpret_cast<const bf16x8*>(_as + ar01);                  \
    bf16x8 af10 = *reinterpret_cast<const bf16x8*>(_as + ar10);                  \
    bf16x8 af11 = *reinterpret_cast<const bf16x8*>(_as + ar11);                  \
    bf16x8 bf00 = *reinterpret_cast<const bf16x8*>(&Bs[buf][br00]);              \
    bf16x8 bf01 = *reinterpret_cast<const bf16x8*>(&Bs[buf][br01]);              \
    bf16x8 bf10 = *reinterpret_cast<const bf16x8*>(&Bs[buf][br10]);              \
    bf16x8 bf11 = *reinterpret_cast<const bf16x8*>(&Bs[buf][br11]);              \
    acc00 = MFMA_(af00, bf00, acc00); acc00 = MFMA_(af01, bf01, acc00);          \
    acc01 = MFMA_(af00, bf10, acc01); acc01 = MFMA_(af01, bf11, acc01);          \
    acc10 = MFMA_(af10, bf00, acc10); acc10 = MFMA_(af11, bf01, acc10);          \
    acc11 = MFMA_(af10, bf10, acc11); acc11 = MFMA_(af11, bf11, acc11);          \
} while (0)

    // ---- prologue: quad0 -> slots 0..3; quad1 parked in regs; B tile 0 ----
    LOADA(0);
    STAGEB(0, 0);
    WRITEA(0);         // compiler waits LOADA(0)
    LOADA(1);
    __syncthreads();

    // ---- main loop (R9 greedy schedule, drain barrier per tile) ----
    // tile t computes slot t%6; at t = 2,6,10,14: write parked quad (t+2)/4
    // into slots (t+2)%6.., then (t <= 10) load quad (t+6)/4.
    for (int tile = 0; tile < TPS; ++tile) {
        if (tile + 1 < TPS) STAGEB(tile + 1, (tile + 1) & 1);
        if ((tile & 3) == 2 && tile + 2 < TPS) {
            WRITEA((tile + 2) % 6);
            if (tile <= 10) LOADA((tile + 6) >> 2);
        }
        COMPUTE(tile % 6, tile & 1);
        __syncthreads();
    }

    // ---- write bf16 partials ----
    {
        unsigned short* Pp = P + ((size_t)split * PROWS + rbase) * F;
        #pragma unroll
        for (int e = 0; e < 4; ++e) {
            Pp[(size_t)(mq * 32 +  0 + g * 4 + e) * F + cq * 32 +      l16] = f2bf(acc00[e]);
            Pp[(size_t)(mq * 32 +  0 + g * 4 + e) * F + cq * 32 + 16 + l16] = f2bf(acc01[e]);
            Pp[(size_t)(mq * 32 + 16 + g * 4 + e) * F + cq * 32 +      l16] = f2bf(acc10[e]);
            Pp[(size_t)(mq * 32 + 16 + g * 4 + e) * F + cq * 32 + 16 + l16] = f2bf(acc11[e]);
        }
    }
#undef LD1
#undef LOADA
#undef WR1
#undef WRITEA
#undef STAGEB
#undef COMPUTE
}

// ---------------------------------------------------------------------------
// Kernel 3: out[r] = relu(sum_s bf2f(P[s][r][:]) + b1) . W2 + b2. grid 5000x256.
// ---------------------------------------------------------------------------
__global__ __launch_bounds__(256) void k_red(const unsigned short* __restrict__ P,
                                             const float* __restrict__ b1,
                                             const float* __restrict__ W2,
                                             const float* __restrict__ b2,
                                             float* __restrict__ out) {
    __shared__ float sred[4];
    const int t   = threadIdx.x;
    const int row = blockIdx.x * 2 + (t >> 7);
    const int c   = t & 127;

    float v = 0.f;
    #pragma unroll
    for (int s = 0; s < SPLITS; ++s) {
        unsigned u = P[((size_t)s * PROWS + row) * F + c];
        v += __builtin_bit_cast(float, u << 16);
    }
    v = fmaxf(v + b1[c], 0.f) * W2[c];

    v += __shfl_xor(v, 1);
    v += __shfl_xor(v, 2);
    v += __shfl_xor(v, 4);
    v += __shfl_xor(v, 8);
    v += __shfl_xor(v, 16);
    v += __shfl_xor(v, 32);
    if ((t & 63) == 0) sred[t >> 6] = v;
    __syncthreads();
    if (t < 2) out[blockIdx.x * 2 + t] = sred[t * 2] + sred[t * 2 + 1] + b2[0];
}

extern "C" void kernel_launch(void* const* d_in, const int* in_sizes, int n_in,
                              void* d_out, int out_size, void* d_ws, size_t ws_size,
                              hipStream_t stream) {
    const float* x  = (const float*)d_in[0];
    const float* a  = (const float*)d_in[1];
    const float* W1 = (const float*)d_in[2];
    const float* b1 = (const float*)d_in[3];
    const float* W2 = (const float*)d_in[4];
    const float* b2 = (const float*)d_in[5];
    float* out = (float*)d_out;

    unsigned short* xwt = (unsigned short*)d_ws;                    // 2.62 MB tiled
    unsigned short* P = (unsigned short*)((char*)d_ws + (size_t)(16 << 20)); // bf16 partials

    k_xw<<<640, 256, 0, stream>>>(x, W1, xwt);
    k_gcn<<<MBLK * SPLITS, 512, 0, stream>>>(a, xwt, P);
    k_red<<<5000, 256, 0, stream>>>(P, b1, W2, b2, out);
}